// Round 5
// baseline (283.940 us; speedup 1.0000x reference)
//
#include <hip/hip_runtime.h>
#include <hip/hip_bf16.h>

typedef unsigned int u32;
typedef unsigned short u16;
typedef __bf16 bf16x8 __attribute__((ext_vector_type(8)));
typedef float f32x4 __attribute__((ext_vector_type(4)));

// ---------- bf16 bit helpers ----------
__device__ __forceinline__ float b2f(u16 s){ union{u32 x; float f;} c; c.x = ((u32)s) << 16; return c.f; }
__device__ __forceinline__ float b2f_lo(u32 u){ union{u32 x; float f;} c; c.x = u << 16; return c.f; }
__device__ __forceinline__ float b2f_hi(u32 u){ union{u32 x; float f;} c; c.x = u & 0xFFFF0000u; return c.f; }
__device__ __forceinline__ u16 f2b(float f){
    union{float f; u32 u;} c; c.f = f;
    u32 r = c.u + 0x7FFFu + ((c.u >> 16) & 1u);
    return (u16)(r >> 16);
}
__device__ __forceinline__ u32 pk(float lo, float hi){
    return (u32)f2b(lo) | ((u32)f2b(hi) << 16);
}
// async global->LDS, 16B per lane (HW: wave-uniform base + lane*16)
__device__ __forceinline__ void gl_lds16(const u16* g, u16* l){
    __builtin_amdgcn_global_load_lds(
        (const __attribute__((address_space(1))) void*)g,
        (__attribute__((address_space(3))) void*)l, 16, 0, 0);
}
#define BARRIER() do { __builtin_amdgcn_s_barrier(); asm volatile("" ::: "memory"); } while(0)
#define SCB __builtin_amdgcn_sched_barrier(0)
#define LD8(p) (*reinterpret_cast<const bf16x8*>(p))

// Problem constants: B=4, T=2048, D=1024, H=16, HD=64, NF=128, chunk C=128, NC=16
// All inputs FLOAT32; OUTPUT is FLOAT32.

// ---------- fp32 -> bf16 bulk convert (x) ----------
__global__ __launch_bounds__(256) void tobf16(const float* __restrict__ in, u16* __restrict__ out)
{
    size_t i = ((size_t)blockIdx.x * 256 + threadIdx.x) * 8;
    float4 a = *reinterpret_cast<const float4*>(in + i);
    float4 b = *reinterpret_cast<const float4*>(in + i + 4);
    uint4 v; v.x = pk(a.x, a.y); v.y = pk(a.z, a.w); v.z = pk(b.x, b.y); v.w = pk(b.z, b.w);
    *reinterpret_cast<uint4*>(out + i) = v;
}

// ---------- all 4 weight transposes (+fp32->bf16) in one dispatch ----------
__global__ __launch_bounds__(256) void transpose_all(const float* __restrict__ Wq, const float* __restrict__ Wk,
                                                     const float* __restrict__ Wv, const float* __restrict__ Wo,
                                                     u16* __restrict__ WTqkv, u16* __restrict__ WTo)
{
    const float* in; u16* out;
    switch (blockIdx.z){
        case 0:  in = Wq; out = WTqkv;           break;
        case 1:  in = Wk; out = WTqkv + 1048576; break;
        case 2:  in = Wv; out = WTqkv + 2097152; break;
        default: in = Wo; out = WTo;             break;
    }
    __shared__ u16 tile[64][72];
    int kb = blockIdx.x * 64, nb = blockIdx.y * 64, tid = threadIdx.x;
#pragma unroll
    for (int i = 0; i < 2; i++){
        int idx = tid + 256*i; int r = idx >> 3; int c8 = (idx & 7) * 8;
        const float* p = &in[(size_t)(kb + r)*1024 + nb + c8];
        float4 lo = *reinterpret_cast<const float4*>(p);
        float4 hi = *reinterpret_cast<const float4*>(p + 4);
        uint4 v;
        v.x = pk(lo.x, lo.y); v.y = pk(lo.z, lo.w);
        v.z = pk(hi.x, hi.y); v.w = pk(hi.z, hi.w);
        *reinterpret_cast<uint4*>(&tile[r][c8]) = v;
    }
    __syncthreads();
#pragma unroll
    for (int i = 0; i < 2; i++){
        int idx = tid + 256*i; int c = idx >> 3; int r8 = (idx & 7) * 8;
        u32 w[4];
#pragma unroll
        for (int j = 0; j < 4; j++)
            w[j] = (u32)tile[r8 + 2*j][c] | ((u32)tile[r8 + 2*j + 1][c] << 16);
        uint4 v; v.x = w[0]; v.y = w[1]; v.z = w[2]; v.w = w[3];
        *reinterpret_cast<uint4*>(&out[(size_t)(nb + c)*1024 + kb + r8]) = v;
    }
}

// ---------- 1-barrier/K-tile counted-vmcnt GEMM: tile 128x256, BK=64, 8 waves (2Mx4N), per-wave 64x64 ----------
// C[8192,N] = A[8192,1024]*W, BT = W^T (N x 1024 row-major).
// MODE 3: N=3072, bf16 remapped QKV out, grid (64,12) = 768 = 3 exact rounds of 256 CUs.
// MODE 2: N=1024, fp32 row-major out,  grid (64,4)  = 256 = 1 exact round.
// LDS 96KB: 2 bufs x { A 128x64 swz, B 256x64 swz }.
// KEY CHANGE vs round 3/4: ONE barrier + ONE vmcnt per K-tile, NO explicit lgkmcnt / phase gates.
// Rationale (round-4 post-mortem): per K-tile per CU the LDS-read floor (~1540 cyc, 128KB @ ~85B/cyc)
// and MFMA floor (~1030 cyc) were SERIALIZED by the barrier-lockstep phases (measured 3325 cyc/K-tile).
// With per-wave compiler-scheduled lgkmcnt and a single end-of-tile barrier, wave i's MFMA overlaps
// wave j's ds_reads -> K-tile ~ max(LDS, MFMA) + skew.
// Hazards: (1) tile-u reads retire before own MFMA (compiler waitcnt) which precedes barrier(u);
// staging B(u+1) writes other-buf.B, last read in tile u-1, retired before barrier(u-1)  -> safe with
// one barrier. (2) vmcnt(2) at end of tile u retires A(u+1)+B(u+1) (in-flight then: A(u+1):2 oldest,
// B(u+1):4, A(u+2):2 newest). Tail: u=14 -> vmcnt(0); u=15 -> no gate/stage/barrier.
// Swizzle (T2, verified 0 conflicts): lds[row*64 + (col ^ ((row&7)<<3))]; linear gl_lds dest +
// inverse-swizzled global source col; reads apply the same XOR.
template<int MODE>
__global__ __launch_bounds__(512, 2) void gemm_1b(const u16* __restrict__ A, const u16* __restrict__ BT,
                                                  float* __restrict__ outf, u16* __restrict__ outh)
{
    __shared__ u16 lds[2][24576];
    const int tid = threadIdx.x;
    const int l = tid & 63, w = tid >> 6;
    const int wr = w >> 2, wc = w & 3;          // 2M x 4N wave grid, per-wave 64x64
    const int fr = l & 15, q = l >> 4;
    const int m0 = blockIdx.x * 128, n0 = blockIdx.y * 256;

    const int srow = tid >> 3;
    const int scol = ((tid & 7) ^ (srow & 7)) << 3;
    const u16* Ag = A  + (size_t)(m0 + srow) * 1024 + scol;
    const u16* Bg = BT + (size_t)(n0 + srow) * 1024 + scol;
    const int sd = tid * 8;

    const int colk0 = (q*8)      ^ ((fr & 7) << 3);
    const int colk1 = (32 + q*8) ^ ((fr & 7) << 3);
    const int aoff = (wr*64 + fr) * 64;
    const int boff = 8192 + (wc*64 + fr) * 64;

    f32x4 acc[4][4] = {};

    auto stgA = [&](int buf, int kt){
#pragma unroll
        for (int i = 0; i < 2; ++i)
            gl_lds16(Ag + (size_t)(i*64)*1024 + kt*64, &lds[buf][i*4096 + sd]);
    };
    auto stgB = [&](int buf, int kt){
#pragma unroll
        for (int j = 0; j < 4; ++j)
            gl_lds16(Bg + (size_t)(j*64)*1024 + kt*64, &lds[buf][8192 + j*4096 + sd]);
    };

    // prologue: A(0),B(0),A(1) = 8 issues; vmcnt(2) retires tile 0 (leaves A(1)x2)
    stgA(0, 0); stgB(0, 0); stgA(1, 1);
    asm volatile("s_waitcnt vmcnt(2)" ::: "memory");
    SCB;
    BARRIER();

#pragma unroll 1
    for (int uu = 0; uu < 8; ++uu){
#pragma unroll
        for (int par = 0; par < 2; ++par){      // u = 2*uu + par, buf = par
            const int u = 2*uu + par;
            u16* Lb = &lds[par][0];
            bf16x8 af[4][2], bf[4][2];

            // all fragment reads for tile u (16 x ds_read_b128); compiler emits
            // fine-grained lgkmcnt before each dependent MFMA
#pragma unroll
            for (int mt = 0; mt < 4; ++mt){
                af[mt][0] = LD8(Lb + aoff + mt*1024 + colk0);
                af[mt][1] = LD8(Lb + aoff + mt*1024 + colk1);
            }
#pragma unroll
            for (int nt = 0; nt < 4; ++nt){
                bf[nt][0] = LD8(Lb + boff + nt*1024 + colk0);
                bf[nt][1] = LD8(Lb + boff + nt*1024 + colk1);
            }
            // prefetch staging (6 VMEM): B(u+1) -> other buf, A(u+2) -> own buf
            if (u < 15) stgB(par ^ 1, u + 1);
            if (u < 14) stgA(par, u + 2);

            // 32 MFMA, K=64
            __builtin_amdgcn_s_setprio(1);
#pragma unroll
            for (int mt = 0; mt < 4; ++mt)
#pragma unroll
                for (int nt = 0; nt < 4; ++nt){
                    acc[mt][nt] = __builtin_amdgcn_mfma_f32_16x16x32_bf16(af[mt][0], bf[nt][0], acc[mt][nt], 0, 0, 0);
                    acc[mt][nt] = __builtin_amdgcn_mfma_f32_16x16x32_bf16(af[mt][1], bf[nt][1], acc[mt][nt], 0, 0, 0);
                }
            __builtin_amdgcn_s_setprio(0);
            SCB;
            // single counted gate + single barrier per K-tile
            if (u < 14){
                asm volatile("s_waitcnt vmcnt(2)" ::: "memory");
                SCB;
                BARRIER();
            } else if (u == 14){
                asm volatile("s_waitcnt vmcnt(0)" ::: "memory");
                SCB;
                BARRIER();
            }
        }
    }

    // epilogue: C/D layout col=lane&15 (N), row=(lane>>4)*4+r (M)
#pragma unroll
    for (int mt = 0; mt < 4; ++mt){
        int row0 = m0 + wr*64 + mt*16 + q*4;
#pragma unroll
        for (int nt = 0; nt < 4; ++nt){
            int col = n0 + wc*64 + nt*16 + fr;
#pragma unroll
            for (int r = 0; r < 4; ++r){
                float val = acc[mt][nt][r];
                int row = row0 + r;
                if (MODE == 2){
                    outf[(size_t)row*1024 + col] = val;
                } else {
                    int which = col >> 10, colw = col & 1023;
                    int h = colw >> 6, d = colw & 63;
                    int bb = row >> 11, tt = row & 2047;
                    outh[(size_t)which*8388608 + (((size_t)(bb*16 + h))*2048 + tt)*64 + d] = f2b(val);
                }
            }
        }
    }
}

// ---------- FAVOR+ feature map via MFMA (q path): phi = exp(x.Wf - 0.5||x||^2)/sqrt(NF) ----------
__global__ __launch_bounds__(256) void featmap_mfma(const u16* __restrict__ xh, const float* __restrict__ Wf,
                                                    u16* __restrict__ xp)
{
    __shared__ u16 Xl[128][72];
    __shared__ u16 Wft[128][72];
    __shared__ float sqp[128][8];
    __shared__ float sql[128];
    int tid = threadIdx.x;
    int lane = tid & 63, w = tid >> 6;
    int m = lane & 15, q = lane >> 4;
    const u16* xb = xh + (size_t)blockIdx.x * 128 * 64;
#pragma unroll
    for (int it = 0; it < 4; it++){
        int idx = tid + 256*it;
        int row = idx >> 3, c8 = (idx & 7) * 8;
        uint4 v = *reinterpret_cast<const uint4*>(xb + (size_t)row*64 + c8);
        *reinterpret_cast<uint4*>(&Xl[row][c8]) = v;
        u32 ww[4] = {v.x, v.y, v.z, v.w};
        float s = 0.f;
#pragma unroll
        for (int j = 0; j < 4; j++){
            float a = b2f_lo(ww[j]), bb = b2f_hi(ww[j]);
            s += a*a + bb*bb;
        }
        sqp[row][idx & 7] = s;
    }
#pragma unroll
    for (int it = 0; it < 8; it++){
        int idx = tid + 256*it;
        int d = idx >> 5, f4 = (idx & 31) * 4;
        float4 v = *reinterpret_cast<const float4*>(Wf + d*128 + f4);
        Wft[f4+0][d] = f2b(v.x); Wft[f4+1][d] = f2b(v.y);
        Wft[f4+2][d] = f2b(v.z); Wft[f4+3][d] = f2b(v.w);
    }
    __syncthreads();
    if (tid < 128){
        float s = 0.f;
#pragma unroll
        for (int j = 0; j < 8; j++) s += sqp[tid][j];
        sql[tid] = s;
    }
    f32x4 acc[2][8] = {};
#pragma unroll
    for (int ks = 0; ks < 2; ks++){
        bf16x8 af[2], bf[8];
#pragma unroll
        for (int mt = 0; mt < 2; mt++)
            af[mt] = *reinterpret_cast<const bf16x8*>(&Xl[32*w + mt*16 + m][ks*32 + q*8]);
#pragma unroll
        for (int nt = 0; nt < 8; nt++)
            bf[nt] = *reinterpret_cast<const bf16x8*>(&Wft[nt*16 + m][ks*32 + q*8]);
#pragma unroll
        for (int mt = 0; mt < 2; mt++)
#pragma unroll
            for (int nt = 0; nt < 8; nt++)
                acc[mt][nt] = __builtin_amdgcn_mfma_f32_16x16x32_bf16(af[mt], bf[nt], acc[mt][nt], 0, 0, 0);
    }
    __syncthreads();
    const float c = 0.08838834764831845f; // 1/sqrt(128)
    u16* xpb = xp + (size_t)blockIdx.x * 128 * 128;
#pragma unroll
    for (int mt = 0; mt < 2; mt++){
#pragma unroll
        for (int r = 0; r < 4; r++){
            int t = 32*w + mt*16 + q*4 + r;
            float hs = 0.5f * sql[t];
#pragma unroll
            for (int nt = 0; nt < 8; nt++){
                int f = nt*16 + m;
                xpb[(size_t)t*128 + f] = f2b(__expf(fminf(acc[mt][nt][r] - hs, 60.f)) * c);
            }
        }
    }
}

// ---------- k path: featmap + per-chunk KV summary fused ----------
// One block = one (bh, chunk): computes kp = phi(k), S^T[d][f] = V^T.kp (MFMA), z = colsum(kp).
struct FM1 { u16 Xl[128][72]; u16 Wft[128][72]; };
union  FMU { FM1 p1; u16 Kpt[128][136]; };
__global__ __launch_bounds__(256) void featmap_sum(const u16* __restrict__ kh, const float* __restrict__ Wf,
                                                   const u16* __restrict__ vh, u16* __restrict__ kp,
                                                   u16* __restrict__ Sa, float* __restrict__ zs)
{
    __shared__ FMU sm;
    __shared__ u16 Vt[64][136];
    __shared__ float sqp[128][8];
    __shared__ float sql[128];
    int blk = blockIdx.x, tid = threadIdx.x;
    int lane = tid & 63, w = tid >> 6;
    int m = lane & 15, q = lane >> 4;
    const u16* xb = kh + (size_t)blk * 128 * 64;
    const u16* vb = vh + (size_t)blk * 128 * 64;   // same (bh,chunk) flat layout
    // stage K-chunk + sq partials
#pragma unroll
    for (int it = 0; it < 4; it++){
        int idx = tid + 256*it;
        int row = idx >> 3, c8 = (idx & 7) * 8;
        uint4 v = *reinterpret_cast<const uint4*>(xb + (size_t)row*64 + c8);
        *reinterpret_cast<uint4*>(&sm.p1.Xl[row][c8]) = v;
        u32 ww[4] = {v.x, v.y, v.z, v.w};
        float s = 0.f;
#pragma unroll
        for (int j = 0; j < 4; j++){
            float a = b2f_lo(ww[j]), bb = b2f_hi(ww[j]);
            s += a*a + bb*bb;
        }
        sqp[row][idx & 7] = s;
    }
    // stage Wf^T
#pragma unroll
    for (int it = 0; it < 8; it++){
        int idx = tid + 256*it;
        int d = idx >> 5, f4 = (idx & 31) * 4;
        float4 v = *reinterpret_cast<const float4*>(Wf + d*128 + f4);
        sm.p1.Wft[f4+0][d] = f2b(v.x); sm.p1.Wft[f4+1][d] = f2b(v.y);
        sm.p1.Wft[f4+2][d] = f2b(v.z); sm.p1.Wft[f4+3][d] = f2b(v.w);
    }
    // stage V transposed
#pragma unroll
    for (int it = 0; it < 4; it++){
        int idx = tid + 256*it;
        int t = idx >> 3, d8 = (idx & 7)*8;
        uint4 v = *reinterpret_cast<const uint4*>(vb + (size_t)t*64 + d8);
        u32 ww[4] = {v.x, v.y, v.z, v.w};
#pragma unroll
        for (int j = 0; j < 4; j++){
            Vt[d8 + 2*j][t]     = (u16)(ww[j] & 0xFFFFu);
            Vt[d8 + 2*j + 1][t] = (u16)(ww[j] >> 16);
        }
    }
    __syncthreads();
    if (tid < 128){
        float s = 0.f;
#pragma unroll
        for (int j = 0; j < 8; j++) s += sqp[tid][j];
        sql[tid] = s;
    }
    // phi MFMA
    f32x4 acc[2][8] = {};
#pragma unroll
    for (int ks = 0; ks < 2; ks++){
        bf16x8 af[2], bf[8];
#pragma unroll
        for (int mt = 0; mt < 2; mt++)
            af[mt] = *reinterpret_cast<const bf16x8*>(&sm.p1.Xl[32*w + mt*16 + m][ks*32 + q*8]);
#pragma unroll
        for (int nt = 0; nt < 8; nt++)
            bf[nt] = *reinterpret_cast<const bf16x8*>(&sm.p1.Wft[nt*16 + m][ks*32 + q*8]);
#pragma unroll
        for (int mt = 0; mt < 2; mt++)
#pragma unroll
            for (int nt = 0; nt < 8; nt++)
                acc[mt][nt] = __builtin_amdgcn_mfma_f32_16x16x32_bf16(af[mt], bf[nt], acc[mt][nt], 0, 0, 0);
    }
    __syncthreads();   // Xl/Wft reads complete (region about to be overwritten), sql visible
    // epilogue: phi -> global kp AND transposed LDS Kpt[f][t]
    const float c = 0.08838834764831845f;
    u16* xpb = kp + (size_t)blk * 128 * 128;
#pragma unroll
    for (int mt = 0; mt < 2; mt++){
#pragma unroll
        for (int r = 0; r < 4; r++){
            int t = 32*w + mt*16 + q*4 + r;
            float hs = 0.5f * sql[t];
#pragma unroll
            for (int nt = 0; nt < 8; nt++){
                int f = nt*16 + m;
                u16 pv = f2b(__expf(fminf(acc[mt][nt][r] - hs, 60.f)) * c);
                xpb[(size_t)t*128 + f] = pv;
                sm.Kpt[f][t] = pv;
            }
        }
    }
    __syncthreads();   // Kpt ready
    // S^T = V^T . kp : A[d][t]=Vt, B[f][t]=Kpt ; wave w -> d rows [16w,16w+16)
    f32x4 acc2[8] = {};
#pragma unroll
    for (int ks = 0; ks < 4; ks++){
        bf16x8 af = *reinterpret_cast<const bf16x8*>(&Vt[16*w + m][ks*32 + q*8]);
        bf16x8 bf[8];
#pragma unroll
        for (int nt = 0; nt < 8; nt++)
            bf[nt] = *reinterpret_cast<const bf16x8*>(&sm.Kpt[nt*16 + m][ks*32 + q*8]);
#pragma unroll
        for (int nt = 0; nt < 8; nt++)
            acc2[nt] = __builtin_amdgcn_mfma_f32_16x16x32_bf16(af, bf[nt], acc2[nt], 0, 0, 0);
    }
    u16* Sb = Sa + (size_t)blk*8192;
#pragma unroll
    for (int nt = 0; nt < 8; nt++){
#pragma unroll
        for (int r = 0; r < 4; r++){
            int d = 16*w + q*4 + r;
            int f = nt*16 + m;
            Sb[(size_t)d*128 + f] = f2b(acc2[nt][r]);
        }
    }
    // z = colsum(kp) from Kpt rows (17-stride bank walk: 2-way, free)
    if (tid < 128){
        float z = 0.f;
#pragma unroll
        for (int t = 0; t < 128; t++) z += b2f(sm.Kpt[tid][t]);
        zs[(size_t)blk*128 + tid] = z;
    }
}

// ---------- exclusive prefix over the 16 chunks (per bh), bf16 in/out ----------
__global__ __launch_bounds__(256) void prefix_chunks(const u16* __restrict__ Sa, u16* __restrict__ Sb,
                                                     float* __restrict__ zs)
{
    int bh = blockIdx.x, seg = blockIdx.y, tid = threadIdx.x;
    const u16* src = Sa + (size_t)bh*16*8192;
    u16*       dst = Sb + (size_t)bh*16*8192;
#pragma unroll
    for (int it = 0; it < 4; it++){
        int e = seg*1024 + it*256 + tid;
        float run = 0.f;
#pragma unroll
        for (int c = 0; c < 16; c++){
            float v = b2f(src[(size_t)c*8192 + e]);
            dst[(size_t)c*8192 + e] = f2b(run);
            run += v;
        }
    }
    if (seg == 0 && tid < 128){
        float run = 0.f; float* zp = zs + (size_t)bh*16*128 + tid;
#pragma unroll
        for (int c = 0; c < 16; c++){ float v = zp[c*128]; zp[c*128] = run; run += v; }
    }
}

// ---------- per-chunk output via MFMA, 8 waves, swizzled LDS ----------
__global__ __launch_bounds__(512) void chunk_out(const u16* __restrict__ qp, const u16* __restrict__ kp,
                                                 const u16* __restrict__ vh, const u16* __restrict__ St,
                                                 const float* __restrict__ zs, u16* __restrict__ y2d)
{
    __shared__ u16 P[128][128];
    __shared__ u16 Vt[64][128];
    __shared__ u16 zl[128];
    int blk = blockIdx.x, tid = threadIdx.x;
    int lane = tid & 63, w = tid >> 6;          // 8 waves
    int m = lane & 15, q = lane >> 4;
    int bh = blk >> 4, c = blk & 15;
    int b = bh >> 4, h = bh & 15, t0 = c*128;
    const u16* qpb = qp + ((size_t)bh*2048 + t0)*128;
    const u16* kpb = kp + ((size_t)bh*2048 + t0)*128;
    const u16* vb  = vh + ((size_t)bh*2048 + t0)*64;
    const u16* Stb = St + (size_t)blk*8192;
    const int xm = (m & 7) << 3;                // read-side swizzle (row&7 == m&7 for all reads)

    if (tid < 128) zl[tid] = f2b(zs[(size_t)blk*128 + tid]);
    // stage V transposed (swizzled): Vt[d][t ^ ((d&7)<<3)]
#pragma unroll
    for (int it = 0; it < 2; it++){
        int idx = tid + 512*it;
        int t = idx >> 3, d8 = (idx & 7)*8;
        uint4 v = *reinterpret_cast<const uint4*>(&vb[(size_t)t*64 + d8]);
        u32 ww[4] = {v.x, v.y, v.z, v.w};
#pragma unroll
        for (int j = 0; j < 4; j++){
            Vt[d8 + 2*j]    [t ^ ((2*j)     << 3)] = (u16)(ww[j] & 0xFFFFu);
            Vt[d8 + 2*j + 1][t ^ ((2*j + 1) << 3)] = (u16)(ww[j] >> 16);
        }
    }
    // zero strict-upper P (cols >= 16*(i+1)), swizzled u32 writes
    {
        int row = tid >> 2, c4 = tid & 3;
        int i = row >> 4, xr = (row & 7) << 3;
        for (int s2 = 16*(i + 1) + c4*2; s2 < 128; s2 += 8)
            *reinterpret_cast<u32*>(&P[row][s2 ^ xr]) = 0;
    }
    // phase 1: 36 lower-tri tiles round-robin over 8 waves (5/5/5/5/4/4/4/4)
    {
        static const unsigned char TIa[36] = {0,1,1,2,2,2,3,3,3,3,4,4,4,4,4,
                                              5,5,5,5,5,5,6,6,6,6,6,6,6,7,7,7,7,7,7,7,7};
        static const unsigned char TJa[36] = {0,0,1,0,1,2,0,1,2,3,0,1,2,3,4,
                                              0,1,2,3,4,5,0,1,2,3,4,5,6,0,1,2,3,4,5,6,7};
        for (int idx = w; idx < 36; idx += 8){
            int i = TIa[idx], j = TJa[idx];
            f32x4 a = {};
            const u16* arow = qpb + (size_t)(i*16 + m)*128 + q*8;
            const u16* brow = kpb + (size_t)(j*16 + m)*128 + q*8;
#pragma unroll
            for (int ks = 0; ks < 4; ks++){
                bf16x8 af = LD8(arow + ks*32);
                bf16x8 bf = LD8(brow + ks*32);
                a = __builtin_amdgcn_mfma_f32_16x16x32_bf16(af, bf, a, 0, 0, 0);
            }
            int scol = j*16 + m;
#pragma unroll
            for (int r = 0; r < 4; r++){
                int trow = i*16 + q*4 + r;
                P[trow][scol ^ ((trow & 7) << 3)] = (scol <= trow) ? f2b(a[r]) : (u16)0;
            }
        }
    }
    __syncthreads();
    // phase 2: wave w -> t-rows [16w,16w+16); acc over d=64 (nt 0-3) + fused denominator
    f32x4 acc4[4] = {};
    f32x4 accd = {};
    bf16x8 ones;
#pragma unroll
    for (int i = 0; i < 8; i++) ones[i] = (__bf16)1.0f;
    for (int ks = 0; ks <= (w >> 1); ks++){
        bf16x8 af = LD8(&P[16*w + m][(ks*32 + q*8) ^ xm]);
        bf16x8 bf4[4];
#pragma unroll
        for (int nt = 0; nt < 4; nt++)
            bf4[nt] = LD8(&Vt[nt*16 + m][(ks*32 + q*8) ^ xm]);
#pragma unroll
        for (int nt = 0; nt < 4; nt++)
            acc4[nt] = __builtin_amdgcn_mfma_f32_16x16x32_bf16(af, bf4[nt], acc4[nt], 0, 0, 0);
        accd = __builtin_amdgcn_mfma_f32_16x16x32_bf16(af, ones, accd, 0, 0, 0);
    }
#pragma unroll
    for (int ks = 0; ks < 4; ks++){
        bf16x8 af = LD8(qpb + (size_t)(16*w + m)*128 + ks*32 + q*8);
        bf16x8 zf = LD8(&zl[ks*32 + q*8]);
        bf16x8 bf4[4];
#pragma unroll
        for (int nt = 0; nt < 4; nt++)
            bf4[nt] = LD8(Stb + (size_t)(nt*16 + m)*128 + ks*32 + q*8);
#pragma unroll
        for (int nt = 0; nt < 4; nt++)
            acc4[nt] = __builtin_amdgcn_mfma_f32_16x16x32_bf16(af, bf4[nt], acc4[nt], 0, 0, 0);
        accd = __builtin_amdgcn_mfma_f32_16x16x32_bf16(af, zf, accd, 0, 0, 0);
    }
    // epilogue: t = 16w + q*4 + r, d = nt*16 + m
#pragma unroll
    for (int nt = 0; nt < 4; nt++){
#pragma unroll
        for (int r = 0; r < 4; r++){
            int t = 16*w + q*4 + r;
            int d = nt*16 + m;
            float den = accd[r] + 1e-6f;
            y2d[((size_t)b*2048 + t0 + t)*1024 + h*64 + d] = f2b(acc4[nt][r] / den);
        }
    }
}

extern "C" void kernel_launch(void* const* d_in, const int* in_sizes, int n_in,
                              void* d_out, int out_size, void* d_ws, size_t ws_size,
                              hipStream_t stream)
{
    (void)in_sizes; (void)n_in; (void)out_size; (void)ws_size;
    const float* x  = (const float*)d_in[0];
    const float* Wq = (const float*)d_in[1];
    const float* Wk = (const float*)d_in[2];
    const float* Wv = (const float*)d_in[3];
    const float* Wo = (const float*)d_in[4];
    const float* Wf = (const float*)d_in[5];
    float* out = (float*)d_out;
    char* ws = (char*)d_ws;

    // workspace layout (lifetime-aliased, ~136.5 MiB)
    u16*   xh    = (u16*)  (ws + 0);           // 16MB x bf16 (dead after QKV gemm)
    u16*   Sa    = (u16*)  (ws + 0);           // alias xh: chunk S^T raw bf16
    u16*   qh    = (u16*)  (ws + 16777216);    // 16MB (dead after featmap q)
    u16*   Sbp   = (u16*)  (ws + 16777216);    // alias qh: prefix S^T
    u16*   kh    = (u16*)  (ws + 33554432);    // 16MB (dead after featmap_sum)
    u16*   y2d   = (u16*)  (ws + 33554432);    // alias kh
    u16*   vh    = (u16*)  (ws + 50331648);    // 16MB
    u16*   qp    = (u16*)  (ws + 67108864);    // 32MB
    u16*   kp    = (u16*)  (ws + 100663296);   // 32MB
    u16*   WTqkv = (u16*)  (ws + 134217728);   // 6MB (3 x 1024x1024 bf16)
    u16*   WTo   = (u16*)  (ws + 140509184);   // 2MB
    float* zs    = (float*)(ws + 142606336);   // 0.5MB

    tobf16<<<4096, 256, 0, stream>>>(x, xh);
    transpose_all<<<dim3(16, 16, 4), 256, 0, stream>>>(Wq, Wk, Wv, Wo, WTqkv, WTo);

    // fused QKV: writes qh, kh, vh (contiguous 16MB blocks starting at qh); 768 blocks = 3 exact rounds
    gemm_1b<3><<<dim3(64, 12), 512, 0, stream>>>(xh, WTqkv, nullptr, qh);

    featmap_mfma<<<1024, 256, 0, stream>>>(qh, Wf, qp);
    featmap_sum<<<1024, 256, 0, stream>>>(kh, Wf, vh, kp, Sa, zs);

    prefix_chunks<<<dim3(64, 8), 256, 0, stream>>>(Sa, Sbp, zs);
    chunk_out<<<1024, 512, 0, stream>>>(qp, kp, vh, Sbp, zs, y2d);

    // out-proj: 256 blocks = 1 exact round
    gemm_1b<2><<<dim3(64, 4), 512, 0, stream>>>(y2d, WTo, out, nullptr);
}

// Round 6
// 283.771 us; speedup vs baseline: 1.0006x; 1.0006x over previous
//
#include <hip/hip_runtime.h>
#include <hip/hip_bf16.h>

typedef unsigned int u32;
typedef unsigned short u16;
typedef __bf16 bf16x8 __attribute__((ext_vector_type(8)));
typedef float f32x4 __attribute__((ext_vector_type(4)));

// ---------- bf16 bit helpers ----------
__device__ __forceinline__ float b2f(u16 s){ union{u32 x; float f;} c; c.x = ((u32)s) << 16; return c.f; }
__device__ __forceinline__ float b2f_lo(u32 u){ union{u32 x; float f;} c; c.x = u << 16; return c.f; }
__device__ __forceinline__ float b2f_hi(u32 u){ union{u32 x; float f;} c; c.x = u & 0xFFFF0000u; return c.f; }
__device__ __forceinline__ u16 f2b(float f){
    union{float f; u32 u;} c; c.f = f;
    u32 r = c.u + 0x7FFFu + ((c.u >> 16) & 1u);
    return (u16)(r >> 16);
}
__device__ __forceinline__ u32 pk(float lo, float hi){
    return (u32)f2b(lo) | ((u32)f2b(hi) << 16);
}
// async global->LDS, 16B per lane (HW: wave-uniform base + lane*16)
__device__ __forceinline__ void gl_lds16(const u16* g, u16* l){
    __builtin_amdgcn_global_load_lds(
        (const __attribute__((address_space(1))) void*)g,
        (__attribute__((address_space(3))) void*)l, 16, 0, 0);
}
#define BARRIER() do { __builtin_amdgcn_s_barrier(); asm volatile("" ::: "memory"); } while(0)
#define SCB __builtin_amdgcn_sched_barrier(0)
#define LD8(p) (*reinterpret_cast<const bf16x8*>(p))
// swizzle keyed on row bits 0-2 XOR 3-5: varies across lanes for BOTH the b16 scatter
// writes (d>>3 = lane&7) and the b128 reads (row&7 = m&7)  -> <=2-4 way everywhere
#define SWZP(r) ((((r) ^ ((r) >> 3)) & 7) << 3)

// Problem constants: B=4, T=2048, D=1024, H=16, HD=64, NF=128, chunk C=128, NC=16
// All inputs FLOAT32; OUTPUT is FLOAT32.

// ---------- fp32 -> bf16 bulk convert (x) ----------
__global__ __launch_bounds__(256) void tobf16(const float* __restrict__ in, u16* __restrict__ out)
{
    size_t i = ((size_t)blockIdx.x * 256 + threadIdx.x) * 8;
    float4 a = *reinterpret_cast<const float4*>(in + i);
    float4 b = *reinterpret_cast<const float4*>(in + i + 4);
    uint4 v; v.x = pk(a.x, a.y); v.y = pk(a.z, a.w); v.z = pk(b.x, b.y); v.w = pk(b.z, b.w);
    *reinterpret_cast<uint4*>(out + i) = v;
}

// ---------- all 4 weight transposes (+fp32->bf16) in one dispatch ----------
__global__ __launch_bounds__(256) void transpose_all(const float* __restrict__ Wq, const float* __restrict__ Wk,
                                                     const float* __restrict__ Wv, const float* __restrict__ Wo,
                                                     u16* __restrict__ WTqkv, u16* __restrict__ WTo)
{
    const float* in; u16* out;
    switch (blockIdx.z){
        case 0:  in = Wq; out = WTqkv;           break;
        case 1:  in = Wk; out = WTqkv + 1048576; break;
        case 2:  in = Wv; out = WTqkv + 2097152; break;
        default: in = Wo; out = WTo;             break;
    }
    __shared__ u16 tile[64][72];
    int kb = blockIdx.x * 64, nb = blockIdx.y * 64, tid = threadIdx.x;
#pragma unroll
    for (int i = 0; i < 2; i++){
        int idx = tid + 256*i; int r = idx >> 3; int c8 = (idx & 7) * 8;
        const float* p = &in[(size_t)(kb + r)*1024 + nb + c8];
        float4 lo = *reinterpret_cast<const float4*>(p);
        float4 hi = *reinterpret_cast<const float4*>(p + 4);
        uint4 v;
        v.x = pk(lo.x, lo.y); v.y = pk(lo.z, lo.w);
        v.z = pk(hi.x, hi.y); v.w = pk(hi.z, hi.w);
        *reinterpret_cast<uint4*>(&tile[r][c8]) = v;
    }
    __syncthreads();
#pragma unroll
    for (int i = 0; i < 2; i++){
        int idx = tid + 256*i; int c = idx >> 3; int r8 = (idx & 7) * 8;
        u32 w[4];
#pragma unroll
        for (int j = 0; j < 4; j++)
            w[j] = (u32)tile[r8 + 2*j][c] | ((u32)tile[r8 + 2*j + 1][c] << 16);
        uint4 v; v.x = w[0]; v.y = w[1]; v.z = w[2]; v.w = w[3];
        *reinterpret_cast<uint4*>(&out[(size_t)(nb + c)*1024 + kb + r8]) = v;
    }
}

// ---------- 1-barrier/K-tile counted-vmcnt GEMM: tile 128x256, BK=64, 8 waves (2Mx4N), per-wave 64x64 ----------
// (unchanged from round 5 — QKV dropped below chunk_out in the profile)
template<int MODE>
__global__ __launch_bounds__(512, 2) void gemm_1b(const u16* __restrict__ A, const u16* __restrict__ BT,
                                                  float* __restrict__ outf, u16* __restrict__ outh)
{
    __shared__ u16 lds[2][24576];
    const int tid = threadIdx.x;
    const int l = tid & 63, w = tid >> 6;
    const int wr = w >> 2, wc = w & 3;          // 2M x 4N wave grid, per-wave 64x64
    const int fr = l & 15, q = l >> 4;
    const int m0 = blockIdx.x * 128, n0 = blockIdx.y * 256;

    const int srow = tid >> 3;
    const int scol = ((tid & 7) ^ (srow & 7)) << 3;
    const u16* Ag = A  + (size_t)(m0 + srow) * 1024 + scol;
    const u16* Bg = BT + (size_t)(n0 + srow) * 1024 + scol;
    const int sd = tid * 8;

    const int colk0 = (q*8)      ^ ((fr & 7) << 3);
    const int colk1 = (32 + q*8) ^ ((fr & 7) << 3);
    const int aoff = (wr*64 + fr) * 64;
    const int boff = 8192 + (wc*64 + fr) * 64;

    f32x4 acc[4][4] = {};

    auto stgA = [&](int buf, int kt){
#pragma unroll
        for (int i = 0; i < 2; ++i)
            gl_lds16(Ag + (size_t)(i*64)*1024 + kt*64, &lds[buf][i*4096 + sd]);
    };
    auto stgB = [&](int buf, int kt){
#pragma unroll
        for (int j = 0; j < 4; ++j)
            gl_lds16(Bg + (size_t)(j*64)*1024 + kt*64, &lds[buf][8192 + j*4096 + sd]);
    };

    // prologue: A(0),B(0),A(1) = 8 issues; vmcnt(2) retires tile 0 (leaves A(1)x2)
    stgA(0, 0); stgB(0, 0); stgA(1, 1);
    asm volatile("s_waitcnt vmcnt(2)" ::: "memory");
    SCB;
    BARRIER();

#pragma unroll 1
    for (int uu = 0; uu < 8; ++uu){
#pragma unroll
        for (int par = 0; par < 2; ++par){      // u = 2*uu + par, buf = par
            const int u = 2*uu + par;
            u16* Lb = &lds[par][0];
            bf16x8 af[4][2], bf[4][2];

#pragma unroll
            for (int mt = 0; mt < 4; ++mt){
                af[mt][0] = LD8(Lb + aoff + mt*1024 + colk0);
                af[mt][1] = LD8(Lb + aoff + mt*1024 + colk1);
            }
#pragma unroll
            for (int nt = 0; nt < 4; ++nt){
                bf[nt][0] = LD8(Lb + boff + nt*1024 + colk0);
                bf[nt][1] = LD8(Lb + boff + nt*1024 + colk1);
            }
            if (u < 15) stgB(par ^ 1, u + 1);
            if (u < 14) stgA(par, u + 2);

            __builtin_amdgcn_s_setprio(1);
#pragma unroll
            for (int mt = 0; mt < 4; ++mt)
#pragma unroll
                for (int nt = 0; nt < 4; ++nt){
                    acc[mt][nt] = __builtin_amdgcn_mfma_f32_16x16x32_bf16(af[mt][0], bf[nt][0], acc[mt][nt], 0, 0, 0);
                    acc[mt][nt] = __builtin_amdgcn_mfma_f32_16x16x32_bf16(af[mt][1], bf[nt][1], acc[mt][nt], 0, 0, 0);
                }
            __builtin_amdgcn_s_setprio(0);
            SCB;
            if (u < 14){
                asm volatile("s_waitcnt vmcnt(2)" ::: "memory");
                SCB;
                BARRIER();
            } else if (u == 14){
                asm volatile("s_waitcnt vmcnt(0)" ::: "memory");
                SCB;
                BARRIER();
            }
        }
    }

    // epilogue: C/D layout col=lane&15 (N), row=(lane>>4)*4+r (M)
#pragma unroll
    for (int mt = 0; mt < 4; ++mt){
        int row0 = m0 + wr*64 + mt*16 + q*4;
#pragma unroll
        for (int nt = 0; nt < 4; ++nt){
            int col = n0 + wc*64 + nt*16 + fr;
#pragma unroll
            for (int r = 0; r < 4; ++r){
                float val = acc[mt][nt][r];
                int row = row0 + r;
                if (MODE == 2){
                    outf[(size_t)row*1024 + col] = val;
                } else {
                    int which = col >> 10, colw = col & 1023;
                    int h = colw >> 6, d = colw & 63;
                    int bb = row >> 11, tt = row & 2047;
                    outh[(size_t)which*8388608 + (((size_t)(bb*16 + h))*2048 + tt)*64 + d] = f2b(val);
                }
            }
        }
    }
}

// ---------- FAVOR+ feature map via MFMA (q path): phi = exp(x.Wf - 0.5||x||^2)/sqrt(NF) ----------
__global__ __launch_bounds__(256) void featmap_mfma(const u16* __restrict__ xh, const float* __restrict__ Wf,
                                                    u16* __restrict__ xp)
{
    __shared__ u16 Xl[128][72];
    __shared__ u16 Wft[128][72];
    __shared__ float sqp[128][8];
    __shared__ float sql[128];
    int tid = threadIdx.x;
    int lane = tid & 63, w = tid >> 6;
    int m = lane & 15, q = lane >> 4;
    const u16* xb = xh + (size_t)blockIdx.x * 128 * 64;
#pragma unroll
    for (int it = 0; it < 4; it++){
        int idx = tid + 256*it;
        int row = idx >> 3, c8 = (idx & 7) * 8;
        uint4 v = *reinterpret_cast<const uint4*>(xb + (size_t)row*64 + c8);
        *reinterpret_cast<uint4*>(&Xl[row][c8]) = v;
        u32 ww[4] = {v.x, v.y, v.z, v.w};
        float s = 0.f;
#pragma unroll
        for (int j = 0; j < 4; j++){
            float a = b2f_lo(ww[j]), bb = b2f_hi(ww[j]);
            s += a*a + bb*bb;
        }
        sqp[row][idx & 7] = s;
    }
#pragma unroll
    for (int it = 0; it < 8; it++){
        int idx = tid + 256*it;
        int d = idx >> 5, f4 = (idx & 31) * 4;
        float4 v = *reinterpret_cast<const float4*>(Wf + d*128 + f4);
        Wft[f4+0][d] = f2b(v.x); Wft[f4+1][d] = f2b(v.y);
        Wft[f4+2][d] = f2b(v.z); Wft[f4+3][d] = f2b(v.w);
    }
    __syncthreads();
    if (tid < 128){
        float s = 0.f;
#pragma unroll
        for (int j = 0; j < 8; j++) s += sqp[tid][j];
        sql[tid] = s;
    }
    f32x4 acc[2][8] = {};
#pragma unroll
    for (int ks = 0; ks < 2; ks++){
        bf16x8 af[2], bf[8];
#pragma unroll
        for (int mt = 0; mt < 2; mt++)
            af[mt] = *reinterpret_cast<const bf16x8*>(&Xl[32*w + mt*16 + m][ks*32 + q*8]);
#pragma unroll
        for (int nt = 0; nt < 8; nt++)
            bf[nt] = *reinterpret_cast<const bf16x8*>(&Wft[nt*16 + m][ks*32 + q*8]);
#pragma unroll
        for (int mt = 0; mt < 2; mt++)
#pragma unroll
            for (int nt = 0; nt < 8; nt++)
                acc[mt][nt] = __builtin_amdgcn_mfma_f32_16x16x32_bf16(af[mt], bf[nt], acc[mt][nt], 0, 0, 0);
    }
    __syncthreads();
    const float c = 0.08838834764831845f; // 1/sqrt(128)
    u16* xpb = xp + (size_t)blockIdx.x * 128 * 128;
#pragma unroll
    for (int mt = 0; mt < 2; mt++){
#pragma unroll
        for (int r = 0; r < 4; r++){
            int t = 32*w + mt*16 + q*4 + r;
            float hs = 0.5f * sql[t];
#pragma unroll
            for (int nt = 0; nt < 8; nt++){
                int f = nt*16 + m;
                xpb[(size_t)t*128 + f] = f2b(__expf(fminf(acc[mt][nt][r] - hs, 60.f)) * c);
            }
        }
    }
}

// ---------- k path: featmap + per-chunk KV summary fused ----------
// One block = one (bh, chunk): computes kp = phi(k), S^T[d][f] = V^T.kp (MFMA), z = colsum(kp).
struct FM1 { u16 Xl[128][72]; u16 Wft[128][72]; };
union  FMU { FM1 p1; u16 Kpt[128][136]; };
__global__ __launch_bounds__(256) void featmap_sum(const u16* __restrict__ kh, const float* __restrict__ Wf,
                                                   const u16* __restrict__ vh, u16* __restrict__ kp,
                                                   u16* __restrict__ Sa, float* __restrict__ zs)
{
    __shared__ FMU sm;
    __shared__ u16 Vt[64][136];
    __shared__ float sqp[128][8];
    __shared__ float sql[128];
    int blk = blockIdx.x, tid = threadIdx.x;
    int lane = tid & 63, w = tid >> 6;
    int m = lane & 15, q = lane >> 4;
    const u16* xb = kh + (size_t)blk * 128 * 64;
    const u16* vb = vh + (size_t)blk * 128 * 64;   // same (bh,chunk) flat layout
    // stage K-chunk + sq partials
#pragma unroll
    for (int it = 0; it < 4; it++){
        int idx = tid + 256*it;
        int row = idx >> 3, c8 = (idx & 7) * 8;
        uint4 v = *reinterpret_cast<const uint4*>(xb + (size_t)row*64 + c8);
        *reinterpret_cast<uint4*>(&sm.p1.Xl[row][c8]) = v;
        u32 ww[4] = {v.x, v.y, v.z, v.w};
        float s = 0.f;
#pragma unroll
        for (int j = 0; j < 4; j++){
            float a = b2f_lo(ww[j]), bb = b2f_hi(ww[j]);
            s += a*a + bb*bb;
        }
        sqp[row][idx & 7] = s;
    }
    // stage Wf^T
#pragma unroll
    for (int it = 0; it < 8; it++){
        int idx = tid + 256*it;
        int d = idx >> 5, f4 = (idx & 31) * 4;
        float4 v = *reinterpret_cast<const float4*>(Wf + d*128 + f4);
        sm.p1.Wft[f4+0][d] = f2b(v.x); sm.p1.Wft[f4+1][d] = f2b(v.y);
        sm.p1.Wft[f4+2][d] = f2b(v.z); sm.p1.Wft[f4+3][d] = f2b(v.w);
    }
    // stage V transposed
#pragma unroll
    for (int it = 0; it < 4; it++){
        int idx = tid + 256*it;
        int t = idx >> 3, d8 = (idx & 7)*8;
        uint4 v = *reinterpret_cast<const uint4*>(vb + (size_t)t*64 + d8);
        u32 ww[4] = {v.x, v.y, v.z, v.w};
#pragma unroll
        for (int j = 0; j < 4; j++){
            Vt[d8 + 2*j][t]     = (u16)(ww[j] & 0xFFFFu);
            Vt[d8 + 2*j + 1][t] = (u16)(ww[j] >> 16);
        }
    }
    __syncthreads();
    if (tid < 128){
        float s = 0.f;
#pragma unroll
        for (int j = 0; j < 8; j++) s += sqp[tid][j];
        sql[tid] = s;
    }
    // phi MFMA
    f32x4 acc[2][8] = {};
#pragma unroll
    for (int ks = 0; ks < 2; ks++){
        bf16x8 af[2], bf[8];
#pragma unroll
        for (int mt = 0; mt < 2; mt++)
            af[mt] = *reinterpret_cast<const bf16x8*>(&sm.p1.Xl[32*w + mt*16 + m][ks*32 + q*8]);
#pragma unroll
        for (int nt = 0; nt < 8; nt++)
            bf[nt] = *reinterpret_cast<const bf16x8*>(&sm.p1.Wft[nt*16 + m][ks*32 + q*8]);
#pragma unroll
        for (int mt = 0; mt < 2; mt++)
#pragma unroll
            for (int nt = 0; nt < 8; nt++)
                acc[mt][nt] = __builtin_amdgcn_mfma_f32_16x16x32_bf16(af[mt], bf[nt], acc[mt][nt], 0, 0, 0);
    }
    __syncthreads();   // Xl/Wft reads complete (region about to be overwritten), sql visible
    // epilogue: phi -> global kp AND transposed LDS Kpt[f][t]
    const float c = 0.08838834764831845f;
    u16* xpb = kp + (size_t)blk * 128 * 128;
#pragma unroll
    for (int mt = 0; mt < 2; mt++){
#pragma unroll
        for (int r = 0; r < 4; r++){
            int t = 32*w + mt*16 + q*4 + r;
            float hs = 0.5f * sql[t];
#pragma unroll
            for (int nt = 0; nt < 8; nt++){
                int f = nt*16 + m;
                u16 pv = f2b(__expf(fminf(acc[mt][nt][r] - hs, 60.f)) * c);
                xpb[(size_t)t*128 + f] = pv;
                sm.Kpt[f][t] = pv;
            }
        }
    }
    __syncthreads();   // Kpt ready
    // S^T = V^T . kp : A[d][t]=Vt, B[f][t]=Kpt ; wave w -> d rows [16w,16w+16)
    f32x4 acc2[8] = {};
#pragma unroll
    for (int ks = 0; ks < 4; ks++){
        bf16x8 af = *reinterpret_cast<const bf16x8*>(&Vt[16*w + m][ks*32 + q*8]);
        bf16x8 bf[8];
#pragma unroll
        for (int nt = 0; nt < 8; nt++)
            bf[nt] = *reinterpret_cast<const bf16x8*>(&sm.Kpt[nt*16 + m][ks*32 + q*8]);
#pragma unroll
        for (int nt = 0; nt < 8; nt++)
            acc2[nt] = __builtin_amdgcn_mfma_f32_16x16x32_bf16(af, bf[nt], acc2[nt], 0, 0, 0);
    }
    u16* Sb = Sa + (size_t)blk*8192;
#pragma unroll
    for (int nt = 0; nt < 8; nt++){
#pragma unroll
        for (int r = 0; r < 4; r++){
            int d = 16*w + q*4 + r;
            int f = nt*16 + m;
            Sb[(size_t)d*128 + f] = f2b(acc2[nt][r]);
        }
    }
    // z = colsum(kp) from Kpt rows (17-stride bank walk: 2-way, free)
    if (tid < 128){
        float z = 0.f;
#pragma unroll
        for (int t = 0; t < 128; t++) z += b2f(sm.Kpt[tid][t]);
        zs[(size_t)blk*128 + tid] = z;
    }
}

// ---------- exclusive prefix over the 16 chunks (per bh), bf16 in/out ----------
__global__ __launch_bounds__(256) void prefix_chunks(const u16* __restrict__ Sa, u16* __restrict__ Sb,
                                                     float* __restrict__ zs)
{
    int bh = blockIdx.x, seg = blockIdx.y, tid = threadIdx.x;
    const u16* src = Sa + (size_t)bh*16*8192;
    u16*       dst = Sb + (size_t)bh*16*8192;
#pragma unroll
    for (int it = 0; it < 4; it++){
        int e = seg*1024 + it*256 + tid;
        float run = 0.f;
#pragma unroll
        for (int c = 0; c < 16; c++){
            float v = b2f(src[(size_t)c*8192 + e]);
            dst[(size_t)c*8192 + e] = f2b(run);
            run += v;
        }
    }
    if (seg == 0 && tid < 128){
        float run = 0.f; float* zp = zs + (size_t)bh*16*128 + tid;
#pragma unroll
        for (int c = 0; c < 16; c++){ float v = zp[c*128]; zp[c*128] = run; run += v; }
    }
}

// ---------- per-chunk output via MFMA, 8 waves, pipelined + conflict-fixed ----------
// Round-6 changes: (1) phase order: qp.St (global-fed, no LDS deps) FIRST so its loads overlap
// Vt staging; z read straight from global (zl removed -> no pre-barrier race). (2) phase-1 QK^T
// fully unrolled (4 + guarded tail) with 2-deep ping-pong register prefetch -> compiler emits
// counted vmcnt, tile t+1 loads fly under tile t MFMA. (3) unified SWZP(row) swizzle for P/Vt:
// key (row ^ row>>3)&7 varies within every store instruction's lane set (d>>3 = lane&7) AND
// every read's (row&7 = m&7) -> <=2-4-way banks everywhere (was 16-way on Vt staging writes).
__global__ __launch_bounds__(512, 4) void chunk_out(const u16* __restrict__ qp, const u16* __restrict__ kp,
                                                    const u16* __restrict__ vh, const u16* __restrict__ St,
                                                    const float* __restrict__ zs, u16* __restrict__ y2d)
{
    __shared__ u16 P[128][128];
    __shared__ u16 Vt[64][128];
    int blk = blockIdx.x, tid = threadIdx.x;
    int lane = tid & 63, w = tid >> 6;          // 8 waves
    int m = lane & 15, q = lane >> 4;
    int bh = blk >> 4, c = blk & 15;
    int b = bh >> 4, h = bh & 15, t0 = c*128;
    const u16*  qpb = qp + ((size_t)bh*2048 + t0)*128;
    const u16*  kpb = kp + ((size_t)bh*2048 + t0)*128;
    const u16*  vb  = vh + ((size_t)bh*2048 + t0)*64;
    const u16*  Stb = St + (size_t)blk*8192;
    const float* zsb = zs + (size_t)blk*128;

    // ---- stage V transposed (SWZP swizzle; per-inst banks 2-way: key has d>>3 = lane&7) ----
#pragma unroll
    for (int it = 0; it < 2; it++){
        int idx = tid + 512*it;
        int t = idx >> 3, d8 = (idx & 7)*8;
        uint4 v = *reinterpret_cast<const uint4*>(&vb[(size_t)t*64 + d8]);
        u32 ww[4] = {v.x, v.y, v.z, v.w};
#pragma unroll
        for (int j = 0; j < 4; j++){
            int d0 = d8 + 2*j, d1 = d0 + 1;
            Vt[d0][t ^ SWZP(d0)] = (u16)(ww[j] & 0xFFFFu);
            Vt[d1][t ^ SWZP(d1)] = (u16)(ww[j] >> 16);
        }
    }
    // ---- zero strict-upper P (cols >= 16*(i+1)), swizzled u32 writes ----
    {
        int row = tid >> 2, c4 = tid & 3;
        int i = row >> 4, xr = SWZP(row);
        for (int s2 = 16*(i + 1) + c4*2; s2 < 128; s2 += 8)
            *reinterpret_cast<u32*>(&P[row][s2 ^ xr]) = 0;
    }

    // ---- phase A: acc = qp . St^T (+ denom z) — pure global feed, overlaps staging above ----
    f32x4 acc4[4] = {};
    f32x4 accd = {};
#pragma unroll
    for (int ks = 0; ks < 4; ks++){
        bf16x8 af = LD8(qpb + (size_t)(16*w + m)*128 + ks*32 + q*8);
        float4 z0 = *reinterpret_cast<const float4*>(zsb + ks*32 + q*8);
        float4 z1 = *reinterpret_cast<const float4*>(zsb + ks*32 + q*8 + 4);
        union { u32 u[4]; bf16x8 v; } zc;
        zc.u[0] = pk(z0.x, z0.y); zc.u[1] = pk(z0.z, z0.w);
        zc.u[2] = pk(z1.x, z1.y); zc.u[3] = pk(z1.z, z1.w);
        bf16x8 bf4[4];
#pragma unroll
        for (int nt = 0; nt < 4; nt++)
            bf4[nt] = LD8(Stb + (size_t)(nt*16 + m)*128 + ks*32 + q*8);
#pragma unroll
        for (int nt = 0; nt < 4; nt++)
            acc4[nt] = __builtin_amdgcn_mfma_f32_16x16x32_bf16(af, bf4[nt], acc4[nt], 0, 0, 0);
        accd = __builtin_amdgcn_mfma_f32_16x16x32_bf16(af, zc.v, accd, 0, 0, 0);
    }

    // ---- phase 1: P = tril(qp.kp^T), 36 tiles over 8 waves, 2-deep register prefetch ----
    {
        static const unsigned char TIa[36] = {0,1,1,2,2,2,3,3,3,3,4,4,4,4,4,
                                              5,5,5,5,5,5,6,6,6,6,6,6,6,7,7,7,7,7,7,7,7};
        static const unsigned char TJa[36] = {0,0,1,0,1,2,0,1,2,3,0,1,2,3,4,
                                              0,1,2,3,4,5,0,1,2,3,4,5,6,0,1,2,3,4,5,6,7};
        bf16x8 fa[2][4], fb[2][4];
        auto ldtile = [&](int idx, bf16x8* A8, bf16x8* B8){
            int i = TIa[idx], j = TJa[idx];
            const u16* ar = qpb + (size_t)(i*16 + m)*128 + q*8;
            const u16* br = kpb + (size_t)(j*16 + m)*128 + q*8;
#pragma unroll
            for (int ks = 0; ks < 4; ks++){ A8[ks] = LD8(ar + ks*32); B8[ks] = LD8(br + ks*32); }
        };
        auto cptile = [&](int idx, bf16x8* A8, bf16x8* B8){
            f32x4 a = {};
#pragma unroll
            for (int ks = 0; ks < 4; ks++)
                a = __builtin_amdgcn_mfma_f32_16x16x32_bf16(A8[ks], B8[ks], a, 0, 0, 0);
            int i = TIa[idx], j = TJa[idx];
            int scol = j*16 + m;
#pragma unroll
            for (int r = 0; r < 4; r++){
                int trow = i*16 + q*4 + r;
                P[trow][scol ^ SWZP(trow)] = (scol <= trow) ? f2b(a[r]) : (u16)0;
            }
        };
        ldtile(w, fa[0], fb[0]);                       // tiles at w, w+8, w+16, w+24 (+w+32 if w<4)
#pragma unroll
        for (int itn = 0; itn < 4; ++itn){
            if (itn < 3)      ldtile(w + (itn+1)*8, fa[(itn+1)&1], fb[(itn+1)&1]);
            else if (w < 4)   ldtile(w + 32,        fa[(itn+1)&1], fb[(itn+1)&1]);
            cptile(w + itn*8, fa[itn&1], fb[itn&1]);
        }
        if (w < 4) cptile(w + 32, fa[0], fb[0]);
    }
    __syncthreads();

    // ---- phase 2: acc += tril(P).V from LDS (triangular: ks <= w>>1), denom += P.1 ----
    bf16x8 ones;
#pragma unroll
    for (int i = 0; i < 8; i++) ones[i] = (__bf16)1.0f;
    {
        int prow = 16*w + m, xp = SWZP(prow);
        int xv[4];
#pragma unroll
        for (int nt = 0; nt < 4; nt++) xv[nt] = SWZP(nt*16 + m);
        for (int ks = 0; ks <= (w >> 1); ks++){
            bf16x8 af = LD8(&P[prow][(ks*32 + q*8) ^ xp]);
            bf16x8 bf4[4];
#pragma unroll
            for (int nt = 0; nt < 4; nt++)
                bf4[nt] = LD8(&Vt[nt*16 + m][(ks*32 + q*8) ^ xv[nt]]);
#pragma unroll
            for (int nt = 0; nt < 4; nt++)
                acc4[nt] = __builtin_amdgcn_mfma_f32_16x16x32_bf16(af, bf4[nt], acc4[nt], 0, 0, 0);
            accd = __builtin_amdgcn_mfma_f32_16x16x32_bf16(af, ones, accd, 0, 0, 0);
        }
    }
    // epilogue: t = 16w + q*4 + r, d = nt*16 + m
#pragma unroll
    for (int nt = 0; nt < 4; nt++){
#pragma unroll
        for (int r = 0; r < 4; r++){
            int t = 16*w + q*4 + r;
            int d = nt*16 + m;
            float den = accd[r] + 1e-6f;
            y2d[((size_t)b*2048 + t0 + t)*1024 + h*64 + d] = f2b(acc4[nt][r] / den);
        }
    }
}

extern "C" void kernel_launch(void* const* d_in, const int* in_sizes, int n_in,
                              void* d_out, int out_size, void* d_ws, size_t ws_size,
                              hipStream_t stream)
{
    (void)in_sizes; (void)n_in; (void)out_size; (void)ws_size;
    const float* x  = (const float*)d_in[0];
    const float* Wq = (const float*)d_in[1];
    const float* Wk = (const float*)d_in[2];
    const float* Wv = (const float*)d_in[3];
    const float* Wo = (const float*)d_in[4];
    const float* Wf = (const float*)d_in[5];
    float* out = (float*)d_out;
    char* ws = (char*)d_ws;

    // workspace layout (lifetime-aliased, ~136.5 MiB)
    u16*   xh    = (u16*)  (ws + 0);           // 16MB x bf16 (dead after QKV gemm)
    u16*   Sa    = (u16*)  (ws + 0);           // alias xh: chunk S^T raw bf16
    u16*   qh    = (u16*)  (ws + 16777216);    // 16MB (dead after featmap q)
    u16*   Sbp   = (u16*)  (ws + 16777216);    // alias qh: prefix S^T
    u16*   kh    = (u16*)  (ws + 33554432);    // 16MB (dead after featmap_sum)
    u16*   y2d   = (u16*)  (ws + 33554432);    // alias kh
    u16*   vh    = (u16*)  (ws + 50331648);    // 16MB
    u16*   qp    = (u16*)  (ws + 67108864);    // 32MB
    u16*   kp    = (u16*)  (ws + 100663296);   // 32MB
    u16*   WTqkv = (u16*)  (ws + 134217728);   // 6MB (3 x 1024x1024 bf16)
    u16*   WTo   = (u16*)  (ws + 140509184);   // 2MB
    float* zs    = (float*)(ws + 142606336);   // 0.5MB

    tobf16<<<4096, 256, 0, stream>>>(x, xh);
    transpose_all<<<dim3(16, 16, 4), 256, 0, stream>>>(Wq, Wk, Wv, Wo, WTqkv, WTo);

    // fused QKV: writes qh, kh, vh (contiguous 16MB blocks starting at qh); 768 blocks = 3 exact rounds
    gemm_1b<3><<<dim3(64, 12), 512, 0, stream>>>(xh, WTqkv, nullptr, qh);

    featmap_mfma<<<1024, 256, 0, stream>>>(qh, Wf, qp);
    featmap_sum<<<1024, 256, 0, stream>>>(kh, Wf, vh, kp, Sa, zs);

    prefix_chunks<<<dim3(64, 8), 256, 0, stream>>>(Sa, Sbp, zs);
    chunk_out<<<1024, 512, 0, stream>>>(qp, kp, vh, Sbp, zs, y2d);

    // out-proj: 256 blocks = 1 exact round
    gemm_1b<2><<<dim3(64, 4), 512, 0, stream>>>(y2d, WTo, out, nullptr);
}

// Round 9
// 256.477 us; speedup vs baseline: 1.1071x; 1.1064x over previous
//
#include <hip/hip_runtime.h>
#include <hip/hip_bf16.h>

typedef unsigned int u32;
typedef unsigned short u16;
typedef __bf16 bf16x8 __attribute__((ext_vector_type(8)));
typedef float f32x4 __attribute__((ext_vector_type(4)));

// ---------- bf16 bit helpers ----------
__device__ __forceinline__ float b2f(u16 s){ union{u32 x; float f;} c; c.x = ((u32)s) << 16; return c.f; }
__device__ __forceinline__ float b2f_lo(u32 u){ union{u32 x; float f;} c; c.x = u << 16; return c.f; }
__device__ __forceinline__ float b2f_hi(u32 u){ union{u32 x; float f;} c; c.x = u & 0xFFFF0000u; return c.f; }
__device__ __forceinline__ u16 f2b(float f){
    union{float f; u32 u;} c; c.f = f;
    u32 r = c.u + 0x7FFFu + ((c.u >> 16) & 1u);
    return (u16)(r >> 16);
}
__device__ __forceinline__ u32 pk(float lo, float hi){
    return (u32)f2b(lo) | ((u32)f2b(hi) << 16);
}
// async global->LDS, 16B per lane (HW: wave-uniform base + lane*16)
__device__ __forceinline__ void gl_lds16(const u16* g, u16* l){
    __builtin_amdgcn_global_load_lds(
        (const __attribute__((address_space(1))) void*)g,
        (__attribute__((address_space(3))) void*)l, 16, 0, 0);
}
#define BARRIER() do { __builtin_amdgcn_s_barrier(); asm volatile("" ::: "memory"); } while(0)
#define SCB __builtin_amdgcn_sched_barrier(0)
#define LD8(p) (*reinterpret_cast<const bf16x8*>(p))
// row-keyed XOR for scratch tensors (qp/kp/St): producers store col^((row&7)<<3);
// consumers (chunk_out) read LDS copies with the same XOR -> 2-way banks (free)
#define SWZR(r) (((r) & 7) << 3)
// write-scatter-friendly swizzle for P/Vt in chunk_out (round-6, conflicts 0.41M)
#define SWZP(r) ((((r) ^ ((r) >> 3)) & 7) << 3)

// Problem constants: B=4, T=2048, D=1024, H=16, HD=64, NF=128, chunk C=128, NC=16
// All inputs FLOAT32; OUTPUT is FLOAT32.

// ---------- fp32 -> bf16 bulk convert (x) ----------
__global__ __launch_bounds__(256) void tobf16(const float* __restrict__ in, u16* __restrict__ out)
{
    size_t i = ((size_t)blockIdx.x * 256 + threadIdx.x) * 8;
    float4 a = *reinterpret_cast<const float4*>(in + i);
    float4 b = *reinterpret_cast<const float4*>(in + i + 4);
    uint4 v; v.x = pk(a.x, a.y); v.y = pk(a.z, a.w); v.z = pk(b.x, b.y); v.w = pk(b.z, b.w);
    *reinterpret_cast<uint4*>(out + i) = v;
}

// ---------- all 4 weight transposes (+fp32->bf16) in one dispatch ----------
__global__ __launch_bounds__(256) void transpose_all(const float* __restrict__ Wq, const float* __restrict__ Wk,
                                                     const float* __restrict__ Wv, const float* __restrict__ Wo,
                                                     u16* __restrict__ WTqkv, u16* __restrict__ WTo)
{
    const float* in; u16* out;
    switch (blockIdx.z){
        case 0:  in = Wq; out = WTqkv;           break;
        case 1:  in = Wk; out = WTqkv + 1048576; break;
        case 2:  in = Wv; out = WTqkv + 2097152; break;
        default: in = Wo; out = WTo;             break;
    }
    __shared__ u16 tile[64][72];
    int kb = blockIdx.x * 64, nb = blockIdx.y * 64, tid = threadIdx.x;
#pragma unroll
    for (int i = 0; i < 2; i++){
        int idx = tid + 256*i; int r = idx >> 3; int c8 = (idx & 7) * 8;
        const float* p = &in[(size_t)(kb + r)*1024 + nb + c8];
        float4 lo = *reinterpret_cast<const float4*>(p);
        float4 hi = *reinterpret_cast<const float4*>(p + 4);
        uint4 v;
        v.x = pk(lo.x, lo.y); v.y = pk(lo.z, lo.w);
        v.z = pk(hi.x, hi.y); v.w = pk(hi.z, hi.w);
        *reinterpret_cast<uint4*>(&tile[r][c8]) = v;
    }
    __syncthreads();
#pragma unroll
    for (int i = 0; i < 2; i++){
        int idx = tid + 256*i; int c = idx >> 3; int r8 = (idx & 7) * 8;
        u32 w[4];
#pragma unroll
        for (int j = 0; j < 4; j++)
            w[j] = (u32)tile[r8 + 2*j][c] | ((u32)tile[r8 + 2*j + 1][c] << 16);
        uint4 v; v.x = w[0]; v.y = w[1]; v.z = w[2]; v.w = w[3];
        *reinterpret_cast<uint4*>(&out[(size_t)(nb + c)*1024 + kb + r8]) = v;
    }
}

// ---------- 1-barrier/K-tile counted-vmcnt GEMM: tile 128x256, BK=64, 8 waves (2Mx4N) ----------
// (unchanged from round 5 — passing, verified)
template<int MODE>
__global__ __launch_bounds__(512, 2) void gemm_1b(const u16* __restrict__ A, const u16* __restrict__ BT,
                                                  float* __restrict__ outf, u16* __restrict__ outh)
{
    __shared__ u16 lds[2][24576];
    const int tid = threadIdx.x;
    const int l = tid & 63, w = tid >> 6;
    const int wr = w >> 2, wc = w & 3;          // 2M x 4N wave grid, per-wave 64x64
    const int fr = l & 15, q = l >> 4;
    const int m0 = blockIdx.x * 128, n0 = blockIdx.y * 256;

    const int srow = tid >> 3;
    const int scol = ((tid & 7) ^ (srow & 7)) << 3;
    const u16* Ag = A  + (size_t)(m0 + srow) * 1024 + scol;
    const u16* Bg = BT + (size_t)(n0 + srow) * 1024 + scol;
    const int sd = tid * 8;

    const int colk0 = (q*8)      ^ ((fr & 7) << 3);
    const int colk1 = (32 + q*8) ^ ((fr & 7) << 3);
    const int aoff = (wr*64 + fr) * 64;
    const int boff = 8192 + (wc*64 + fr) * 64;

    f32x4 acc[4][4] = {};

    auto stgA = [&](int buf, int kt){
#pragma unroll
        for (int i = 0; i < 2; ++i)
            gl_lds16(Ag + (size_t)(i*64)*1024 + kt*64, &lds[buf][i*4096 + sd]);
    };
    auto stgB = [&](int buf, int kt){
#pragma unroll
        for (int j = 0; j < 4; ++j)
            gl_lds16(Bg + (size_t)(j*64)*1024 + kt*64, &lds[buf][8192 + j*4096 + sd]);
    };

    // prologue: A(0),B(0),A(1) = 8 issues; vmcnt(2) retires tile 0 (leaves A(1)x2)
    stgA(0, 0); stgB(0, 0); stgA(1, 1);
    asm volatile("s_waitcnt vmcnt(2)" ::: "memory");
    SCB;
    BARRIER();

#pragma unroll 1
    for (int uu = 0; uu < 8; ++uu){
#pragma unroll
        for (int par = 0; par < 2; ++par){      // u = 2*uu + par, buf = par
            const int u = 2*uu + par;
            u16* Lb = &lds[par][0];
            bf16x8 af[4][2], bf[4][2];

#pragma unroll
            for (int mt = 0; mt < 4; ++mt){
                af[mt][0] = LD8(Lb + aoff + mt*1024 + colk0);
                af[mt][1] = LD8(Lb + aoff + mt*1024 + colk1);
            }
#pragma unroll
            for (int nt = 0; nt < 4; ++nt){
                bf[nt][0] = LD8(Lb + boff + nt*1024 + colk0);
                bf[nt][1] = LD8(Lb + boff + nt*1024 + colk1);
            }
            if (u < 15) stgB(par ^ 1, u + 1);
            if (u < 14) stgA(par, u + 2);

            __builtin_amdgcn_s_setprio(1);
#pragma unroll
            for (int mt = 0; mt < 4; ++mt)
#pragma unroll
                for (int nt = 0; nt < 4; ++nt){
                    acc[mt][nt] = __builtin_amdgcn_mfma_f32_16x16x32_bf16(af[mt][0], bf[nt][0], acc[mt][nt], 0, 0, 0);
                    acc[mt][nt] = __builtin_amdgcn_mfma_f32_16x16x32_bf16(af[mt][1], bf[nt][1], acc[mt][nt], 0, 0, 0);
                }
            __builtin_amdgcn_s_setprio(0);
            SCB;
            if (u < 14){
                asm volatile("s_waitcnt vmcnt(2)" ::: "memory");
                SCB;
                BARRIER();
            } else if (u == 14){
                asm volatile("s_waitcnt vmcnt(0)" ::: "memory");
                SCB;
                BARRIER();
            }
        }
    }

    // epilogue: C/D layout col=lane&15 (N), row=(lane>>4)*4+r (M)
#pragma unroll
    for (int mt = 0; mt < 4; ++mt){
        int row0 = m0 + wr*64 + mt*16 + q*4;
#pragma unroll
        for (int nt = 0; nt < 4; ++nt){
            int col = n0 + wc*64 + nt*16 + fr;
#pragma unroll
            for (int r = 0; r < 4; ++r){
                float val = acc[mt][nt][r];
                int row = row0 + r;
                if (MODE == 2){
                    outf[(size_t)row*1024 + col] = val;
                } else {
                    int which = col >> 10, colw = col & 1023;
                    int h = colw >> 6, d = colw & 63;
                    int bb = row >> 11, tt = row & 2047;
                    outh[(size_t)which*8388608 + (((size_t)(bb*16 + h))*2048 + tt)*64 + d] = f2b(val);
                }
            }
        }
    }
}

// ---------- FAVOR+ feature map via MFMA (q path): phi = exp(x.Wf - 0.5||x||^2)/sqrt(NF) ----------
// qp is stored PRE-SWIZZLED (col f ^ SWZR(t)) — consumed only by chunk_out which stages it
// linearly into LDS and reads with the same XOR (conflict-free b128).
__global__ __launch_bounds__(256) void featmap_mfma(const u16* __restrict__ xh, const float* __restrict__ Wf,
                                                    u16* __restrict__ xp)
{
    __shared__ u16 Xl[128][72];
    __shared__ u16 Wft[128][72];
    __shared__ float sqp[128][8];
    __shared__ float sql[128];
    int tid = threadIdx.x;
    int lane = tid & 63, w = tid >> 6;
    int m = lane & 15, q = lane >> 4;
    const u16* xb = xh + (size_t)blockIdx.x * 128 * 64;
#pragma unroll
    for (int it = 0; it < 4; it++){
        int idx = tid + 256*it;
        int row = idx >> 3, c8 = (idx & 7) * 8;
        uint4 v = *reinterpret_cast<const uint4*>(xb + (size_t)row*64 + c8);
        *reinterpret_cast<uint4*>(&Xl[row][c8]) = v;
        u32 ww[4] = {v.x, v.y, v.z, v.w};
        float s = 0.f;
#pragma unroll
        for (int j = 0; j < 4; j++){
            float a = b2f_lo(ww[j]), bb = b2f_hi(ww[j]);
            s += a*a + bb*bb;
        }
        sqp[row][idx & 7] = s;
    }
#pragma unroll
    for (int it = 0; it < 8; it++){
        int idx = tid + 256*it;
        int d = idx >> 5, f4 = (idx & 31) * 4;
        float4 v = *reinterpret_cast<const float4*>(Wf + d*128 + f4);
        Wft[f4+0][d] = f2b(v.x); Wft[f4+1][d] = f2b(v.y);
        Wft[f4+2][d] = f2b(v.z); Wft[f4+3][d] = f2b(v.w);
    }
    __syncthreads();
    if (tid < 128){
        float s = 0.f;
#pragma unroll
        for (int j = 0; j < 8; j++) s += sqp[tid][j];
        sql[tid] = s;
    }
    f32x4 acc[2][8] = {};
#pragma unroll
    for (int ks = 0; ks < 2; ks++){
        bf16x8 af[2], bf[8];
#pragma unroll
        for (int mt = 0; mt < 2; mt++)
            af[mt] = *reinterpret_cast<const bf16x8*>(&Xl[32*w + mt*16 + m][ks*32 + q*8]);
#pragma unroll
        for (int nt = 0; nt < 8; nt++)
            bf[nt] = *reinterpret_cast<const bf16x8*>(&Wft[nt*16 + m][ks*32 + q*8]);
#pragma unroll
        for (int mt = 0; mt < 2; mt++)
#pragma unroll
            for (int nt = 0; nt < 8; nt++)
                acc[mt][nt] = __builtin_amdgcn_mfma_f32_16x16x32_bf16(af[mt], bf[nt], acc[mt][nt], 0, 0, 0);
    }
    __syncthreads();
    const float c = 0.08838834764831845f; // 1/sqrt(128)
    u16* xpb = xp + (size_t)blockIdx.x * 128 * 128;
#pragma unroll
    for (int mt = 0; mt < 2; mt++){
#pragma unroll
        for (int r = 0; r < 4; r++){
            int t = 32*w + mt*16 + q*4 + r;
            float hs = 0.5f * sql[t];
#pragma unroll
            for (int nt = 0; nt < 8; nt++){
                int f = nt*16 + m;
                xpb[(size_t)t*128 + (f ^ SWZR(t))] = f2b(__expf(fminf(acc[mt][nt][r] - hs, 60.f)) * c);
            }
        }
    }
}

// ---------- k path: featmap + per-chunk KV summary fused ----------
// kp and Sa stored PRE-SWIZZLED (SWZR) for chunk_out's LDS staging; internal Kpt unchanged.
struct FM1 { u16 Xl[128][72]; u16 Wft[128][72]; };
union  FMU { FM1 p1; u16 Kpt[128][136]; };
__global__ __launch_bounds__(256) void featmap_sum(const u16* __restrict__ kh, const float* __restrict__ Wf,
                                                   const u16* __restrict__ vh, u16* __restrict__ kp,
                                                   u16* __restrict__ Sa, float* __restrict__ zs)
{
    __shared__ FMU sm;
    __shared__ u16 Vt[64][136];
    __shared__ float sqp[128][8];
    __shared__ float sql[128];
    int blk = blockIdx.x, tid = threadIdx.x;
    int lane = tid & 63, w = tid >> 6;
    int m = lane & 15, q = lane >> 4;
    const u16* xb = kh + (size_t)blk * 128 * 64;
    const u16* vb = vh + (size_t)blk * 128 * 64;   // same (bh,chunk) flat layout
    // stage K-chunk + sq partials
#pragma unroll
    for (int it = 0; it < 4; it++){
        int idx = tid + 256*it;
        int row = idx >> 3, c8 = (idx & 7) * 8;
        uint4 v = *reinterpret_cast<const uint4*>(xb + (size_t)row*64 + c8);
        *reinterpret_cast<uint4*>(&sm.p1.Xl[row][c8]) = v;
        u32 ww[4] = {v.x, v.y, v.z, v.w};
        float s = 0.f;
#pragma unroll
        for (int j = 0; j < 4; j++){
            float a = b2f_lo(ww[j]), bb = b2f_hi(ww[j]);
            s += a*a + bb*bb;
        }
        sqp[row][idx & 7] = s;
    }
    // stage Wf^T
#pragma unroll
    for (int it = 0; it < 8; it++){
        int idx = tid + 256*it;
        int d = idx >> 5, f4 = (idx & 31) * 4;
        float4 v = *reinterpret_cast<const float4*>(Wf + d*128 + f4);
        sm.p1.Wft[f4+0][d] = f2b(v.x); sm.p1.Wft[f4+1][d] = f2b(v.y);
        sm.p1.Wft[f4+2][d] = f2b(v.z); sm.p1.Wft[f4+3][d] = f2b(v.w);
    }
    // stage V transposed
#pragma unroll
    for (int it = 0; it < 4; it++){
        int idx = tid + 256*it;
        int t = idx >> 3, d8 = (idx & 7)*8;
        uint4 v = *reinterpret_cast<const uint4*>(vb + (size_t)t*64 + d8);
        u32 ww[4] = {v.x, v.y, v.z, v.w};
#pragma unroll
        for (int j = 0; j < 4; j++){
            Vt[d8 + 2*j][t]     = (u16)(ww[j] & 0xFFFFu);
            Vt[d8 + 2*j + 1][t] = (u16)(ww[j] >> 16);
        }
    }
    __syncthreads();
    if (tid < 128){
        float s = 0.f;
#pragma unroll
        for (int j = 0; j < 8; j++) s += sqp[tid][j];
        sql[tid] = s;
    }
    // phi MFMA
    f32x4 acc[2][8] = {};
#pragma unroll
    for (int ks = 0; ks < 2; ks++){
        bf16x8 af[2], bf[8];
#pragma unroll
        for (int mt = 0; mt < 2; mt++)
            af[mt] = *reinterpret_cast<const bf16x8*>(&sm.p1.Xl[32*w + mt*16 + m][ks*32 + q*8]);
#pragma unroll
        for (int nt = 0; nt < 8; nt++)
            bf[nt] = *reinterpret_cast<const bf16x8*>(&sm.p1.Wft[nt*16 + m][ks*32 + q*8]);
#pragma unroll
        for (int mt = 0; mt < 2; mt++)
#pragma unroll
            for (int nt = 0; nt < 8; nt++)
                acc[mt][nt] = __builtin_amdgcn_mfma_f32_16x16x32_bf16(af[mt], bf[nt], acc[mt][nt], 0, 0, 0);
    }
    __syncthreads();   // Xl/Wft reads complete (region about to be overwritten), sql visible
    // epilogue: phi -> global kp (pre-swizzled) AND transposed LDS Kpt[f][t]
    const float c = 0.08838834764831845f;
    u16* xpb = kp + (size_t)blk * 128 * 128;
#pragma unroll
    for (int mt = 0; mt < 2; mt++){
#pragma unroll
        for (int r = 0; r < 4; r++){
            int t = 32*w + mt*16 + q*4 + r;
            float hs = 0.5f * sql[t];
#pragma unroll
            for (int nt = 0; nt < 8; nt++){
                int f = nt*16 + m;
                u16 pv = f2b(__expf(fminf(acc[mt][nt][r] - hs, 60.f)) * c);
                xpb[(size_t)t*128 + (f ^ SWZR(t))] = pv;
                sm.Kpt[f][t] = pv;
            }
        }
    }
    __syncthreads();   // Kpt ready
    // S^T = V^T . kp : A[d][t]=Vt, B[f][t]=Kpt ; wave w -> d rows [16w,16w+16)
    f32x4 acc2[8] = {};
#pragma unroll
    for (int ks = 0; ks < 4; ks++){
        bf16x8 af = *reinterpret_cast<const bf16x8*>(&Vt[16*w + m][ks*32 + q*8]);
        bf16x8 bf[8];
#pragma unroll
        for (int nt = 0; nt < 8; nt++)
            bf[nt] = *reinterpret_cast<const bf16x8*>(&sm.Kpt[nt*16 + m][ks*32 + q*8]);
#pragma unroll
        for (int nt = 0; nt < 8; nt++)
            acc2[nt] = __builtin_amdgcn_mfma_f32_16x16x32_bf16(af, bf[nt], acc2[nt], 0, 0, 0);
    }
    u16* Sb = Sa + (size_t)blk*8192;
#pragma unroll
    for (int nt = 0; nt < 8; nt++){
#pragma unroll
        for (int r = 0; r < 4; r++){
            int d = 16*w + q*4 + r;
            int f = nt*16 + m;
            Sb[(size_t)d*128 + (f ^ SWZR(d))] = f2b(acc2[nt][r]);
        }
    }
    // z = colsum(kp) from Kpt rows (17-stride bank walk: 2-way, free)
    if (tid < 128){
        float z = 0.f;
#pragma unroll
        for (int t = 0; t < 128; t++) z += b2f(sm.Kpt[tid][t]);
        zs[(size_t)blk*128 + tid] = z;
    }
}

// ---------- exclusive prefix over the 16 chunks (per bh), bf16 in/out ----------
// Elementwise over the flat per-chunk arrays -> transparent to the SWZR pre-swizzle.
__global__ __launch_bounds__(256) void prefix_chunks(const u16* __restrict__ Sa, u16* __restrict__ Sb,
                                                     float* __restrict__ zs)
{
    int bh = blockIdx.x, seg = blockIdx.y, tid = threadIdx.x;
    const u16* src = Sa + (size_t)bh*16*8192;
    u16*       dst = Sb + (size_t)bh*16*8192;
#pragma unroll
    for (int it = 0; it < 4; it++){
        int e = seg*1024 + it*256 + tid;
        float run = 0.f;
#pragma unroll
        for (int c = 0; c < 16; c++){
            float v = b2f(src[(size_t)c*8192 + e]);
            dst[(size_t)c*8192 + e] = f2b(run);
            run += v;
        }
    }
    if (seg == 0 && tid < 128){
        float run = 0.f; float* zp = zs + (size_t)bh*16*128 + tid;
#pragma unroll
        for (int c = 0; c < 16; c++){ float v = zp[c*128]; zp[c*128] = run; run += v; }
    }
}

// ---------- per-chunk output, fully LDS-fed (round-8: de-risked sync) ----------
// Design thesis unchanged (round-6 lesson): scattered 16-segment global gathers are the
// ~60 µs cost; qp/kp/St are pre-swizzled at producers and staged here with 10 LINEAR
// coalesced global_load_lds issues + 2 coalesced V loads; all fragment reads are
// conflict-free LDS b128. Sync de-risked vs round-7: NO counted vmcnt gates — P-zeroing
// (LDS-only) overlaps the load flight, then ONE vmcnt(0)+barrier, then all compute.
__global__ __launch_bounds__(512) void chunk_out(const u16* __restrict__ qp, const u16* __restrict__ kp,
                                                 const u16* __restrict__ vh, const u16* __restrict__ St,
                                                 const float* __restrict__ zs, u16* __restrict__ y2d)
{
    __shared__ u16 QpL[16384];      // 128x128, content SWZR-swizzled (as stored in global)
    __shared__ u16 KpL[16384];
    __shared__ u16 StL[8192];       // 64x128, SWZR
    __shared__ u16 Vt[64][128];     // built by scatter, SWZP
    __shared__ u16 P[128][128];     // SWZP
    int blk = blockIdx.x, tid = threadIdx.x;
    int lane = tid & 63, w = tid >> 6;          // 8 waves
    int m = lane & 15, q = lane >> 4;
    int bh = blk >> 4, c = blk & 15;
    int b = bh >> 4, h = bh & 15, t0 = c*128;
    const u16*  qpb = qp + ((size_t)bh*2048 + t0)*128;
    const u16*  kpb = kp + ((size_t)bh*2048 + t0)*128;
    const u16*  vb  = vh + ((size_t)bh*2048 + t0)*64;
    const u16*  Stb = St + (size_t)blk*8192;
    const float* zsb = zs + (size_t)blk*128;
    const int xm8 = SWZR(m);                    // fragment-read XOR (row&7 == m&7 everywhere)
    const int sd = tid * 8;                     // u16; HW dest = wave-uniform base + lane*16B

    // ---- issue ALL staging up front: St(2), qp(4), kp(4) async + V(2 reg loads) ----
#pragma unroll
    for (int i = 0; i < 2; ++i) gl_lds16(Stb + i*4096 + sd, StL + i*4096 + sd);
#pragma unroll
    for (int i = 0; i < 4; ++i) gl_lds16(qpb + i*4096 + sd, QpL + i*4096 + sd);
#pragma unroll
    for (int i = 0; i < 4; ++i) gl_lds16(kpb + i*4096 + sd, KpL + i*4096 + sd);
    uint4 v0 = *reinterpret_cast<const uint4*>(vb + (size_t)(tid >> 3)*64 + (tid & 7)*8);
    uint4 v1 = *reinterpret_cast<const uint4*>(vb + (size_t)((tid + 512) >> 3)*64 + (tid & 7)*8);

    // ---- zero strict-upper P while the loads fly (LDS-only, no staged-region deps) ----
    {
        int row = tid >> 2, c4 = tid & 3;
        int i = row >> 4, xr = SWZP(row);
        for (int s2 = 16*(i + 1) + c4*2; s2 < 128; s2 += 8)
            *reinterpret_cast<u32*>(&P[row][s2 ^ xr]) = 0;
    }
    SCB;
    asm volatile("s_waitcnt vmcnt(0)" ::: "memory");   // conservative single drain
    SCB;
    BARRIER();

    // ---- Vt scatter (v0/v1 ready) ----
    {
        int t = tid >> 3, d8 = (tid & 7)*8;
        u32 ww0[4] = {v0.x, v0.y, v0.z, v0.w};
        u32 ww1[4] = {v1.x, v1.y, v1.z, v1.w};
#pragma unroll
        for (int j = 0; j < 4; j++){
            int d0 = d8 + 2*j, d1 = d0 + 1;
            Vt[d0][t ^ SWZP(d0)]        = (u16)(ww0[j] & 0xFFFFu);
            Vt[d1][t ^ SWZP(d1)]        = (u16)(ww0[j] >> 16);
            Vt[d0][(t + 64) ^ SWZP(d0)] = (u16)(ww1[j] & 0xFFFFu);
            Vt[d1][(t + 64) ^ SWZP(d1)] = (u16)(ww1[j] >> 16);
        }
    }

    // ---- phase A: acc = qp . St^T (+ denom z), all LDS-fed ----
    f32x4 acc4[4] = {};
    f32x4 accd = {};
#pragma unroll
    for (int ks = 0; ks < 4; ks++){
        bf16x8 af = LD8(QpL + (size_t)(16*w + m)*128 + ((ks*32 + q*8) ^ xm8));
        float4 z0 = *reinterpret_cast<const float4*>(zsb + ks*32 + q*8);
        float4 z1 = *reinterpret_cast<const float4*>(zsb + ks*32 + q*8 + 4);
        union { u32 u[4]; bf16x8 v; } zc;
        zc.u[0] = pk(z0.x, z0.y); zc.u[1] = pk(z0.z, z0.w);
        zc.u[2] = pk(z1.x, z1.y); zc.u[3] = pk(z1.z, z1.w);
        bf16x8 bf4[4];
#pragma unroll
        for (int nt = 0; nt < 4; nt++)
            bf4[nt] = LD8(StL + (size_t)(nt*16 + m)*128 + ((ks*32 + q*8) ^ xm8));
#pragma unroll
        for (int nt = 0; nt < 4; nt++)
            acc4[nt] = __builtin_amdgcn_mfma_f32_16x16x32_bf16(af, bf4[nt], acc4[nt], 0, 0, 0);
        accd = __builtin_amdgcn_mfma_f32_16x16x32_bf16(af, zc.v, accd, 0, 0, 0);
    }

    // ---- phase 1: P = tril(qp.kp^T), 36 tiles over 8 waves, all LDS-fed ----
    {
        static const unsigned char TIa[36] = {0,1,1,2,2,2,3,3,3,3,4,4,4,4,4,
                                              5,5,5,5,5,5,6,6,6,6,6,6,6,7,7,7,7,7,7,7,7};
        static const unsigned char TJa[36] = {0,0,1,0,1,2,0,1,2,3,0,1,2,3,4,
                                              0,1,2,3,4,5,0,1,2,3,4,5,6,0,1,2,3,4,5,6,7};
        auto dotile = [&](int idx){
            int i = TIa[idx], j = TJa[idx];
            const u16* ar = QpL + (size_t)(i*16 + m)*128;
            const u16* br = KpL + (size_t)(j*16 + m)*128;
            f32x4 a = {};
#pragma unroll
            for (int ks = 0; ks < 4; ks++){
                bf16x8 af = LD8(ar + ((ks*32 + q*8) ^ xm8));
                bf16x8 bf = LD8(br + ((ks*32 + q*8) ^ xm8));
                a = __builtin_amdgcn_mfma_f32_16x16x32_bf16(af, bf, a, 0, 0, 0);
            }
            int scol = j*16 + m;
#pragma unroll
            for (int r = 0; r < 4; r++){
                int trow = i*16 + q*4 + r;
                P[trow][scol ^ SWZP(trow)] = (scol <= trow) ? f2b(a[r]) : (u16)0;
            }
        };
#pragma unroll
        for (int itn = 0; itn < 4; ++itn) dotile(w + itn*8);
        if (w < 4) dotile(w + 32);
    }
    __syncthreads();

    // ---- phase 2: acc += tril(P).V from LDS (triangular: ks <= w>>1), denom += P.1 ----
    bf16x8 ones;
#pragma unroll
    for (int i = 0; i < 8; i++) ones[i] = (__bf16)1.0f;
    {
        int prow = 16*w + m, xp = SWZP(prow);
        int xv[4];
#pragma unroll
        for (int nt = 0; nt < 4; nt++) xv[nt] = SWZP(nt*16 + m);
        for (int ks = 0; ks <= (w >> 1); ks++){
            bf16x8 af = LD8(&P[prow][(ks*32 + q*8) ^ xp]);
            bf16x8 bf4[4];
#pragma unroll
            for (int nt = 0; nt < 4; nt++)
                bf4[nt] = LD8(&Vt[nt*16 + m][(ks*32 + q*8) ^ xv[nt]]);
#pragma unroll
            for (int nt = 0; nt < 4; nt++)
                acc4[nt] = __builtin_amdgcn_mfma_f32_16x16x32_bf16(af, bf4[nt], acc4[nt], 0, 0, 0);
            accd = __builtin_amdgcn_mfma_f32_16x16x32_bf16(af, ones, accd, 0, 0, 0);
        }
    }
    // epilogue: t = 16w + q*4 + r, d = nt*16 + m
#pragma unroll
    for (int nt = 0; nt < 4; nt++){
#pragma unroll
        for (int r = 0; r < 4; r++){
            int t = 16*w + q*4 + r;
            int d = nt*16 + m;
            float den = accd[r] + 1e-6f;
            y2d[((size_t)b*2048 + t0 + t)*1024 + h*64 + d] = f2b(acc4[nt][r] / den);
        }
    }
}

extern "C" void kernel_launch(void* const* d_in, const int* in_sizes, int n_in,
                              void* d_out, int out_size, void* d_ws, size_t ws_size,
                              hipStream_t stream)
{
    (void)in_sizes; (void)n_in; (void)out_size; (void)ws_size;
    const float* x  = (const float*)d_in[0];
    const float* Wq = (const float*)d_in[1];
    const float* Wk = (const float*)d_in[2];
    const float* Wv = (const float*)d_in[3];
    const float* Wo = (const float*)d_in[4];
    const float* Wf = (const float*)d_in[5];
    float* out = (float*)d_out;
    char* ws = (char*)d_ws;

    // workspace layout (lifetime-aliased, ~136.5 MiB)
    u16*   xh    = (u16*)  (ws + 0);           // 16MB x bf16 (dead after QKV gemm)
    u16*   Sa    = (u16*)  (ws + 0);           // alias xh: chunk S^T raw bf16 (SWZR-swizzled)
    u16*   qh    = (u16*)  (ws + 16777216);    // 16MB (dead after featmap q)
    u16*   Sbp   = (u16*)  (ws + 16777216);    // alias qh: prefix S^T (SWZR)
    u16*   kh    = (u16*)  (ws + 33554432);    // 16MB (dead after featmap_sum)
    u16*   y2d   = (u16*)  (ws + 33554432);    // alias kh
    u16*   vh    = (u16*)  (ws + 50331648);    // 16MB
    u16*   qp    = (u16*)  (ws + 67108864);    // 32MB (SWZR)
    u16*   kp    = (u16*)  (ws + 100663296);   // 32MB (SWZR)
    u16*   WTqkv = (u16*)  (ws + 134217728);   // 6MB (3 x 1024x1024 bf16)
    u16*   WTo   = (u16*)  (ws + 140509184);   // 2MB
    float* zs    = (float*)(ws + 142606336);   // 0.5MB

    tobf16<<<4096, 256, 0, stream>>>(x, xh);
    transpose_all<<<dim3(16, 16, 4), 256, 0, stream>>>(Wq, Wk, Wv, Wo, WTqkv, WTo);

    // fused QKV: writes qh, kh, vh (contiguous 16MB blocks starting at qh); 768 blocks = 3 exact rounds
    gemm_1b<3><<<dim3(64, 12), 512, 0, stream>>>(xh, WTqkv, nullptr, qh);

    featmap_mfma<<<1024, 256, 0, stream>>>(qh, Wf, qp);
    featmap_sum<<<1024, 256, 0, stream>>>(kh, Wf, vh, kp, Sa, zs);

    prefix_chunks<<<dim3(64, 8), 256, 0, stream>>>(Sa, Sbp, zs);
    chunk_out<<<1024, 512, 0, stream>>>(qp, kp, vh, Sbp, zs, y2d);

    // out-proj: 256 blocks = 1 exact round
    gemm_1b<2><<<dim3(64, 4), 512, 0, stream>>>(y2d, WTo, out, nullptr);
}